// Round 1
// baseline (126.169 us; speedup 1.0000x reference)
//
#include <hip/hip_runtime.h>
#include <hip/hip_bf16.h>

// Problem constants (fixed by setup_inputs):
//   n = 4096, dc = 4096, nb = 4, db = 2048, T buckets = 5000
#define N_SAMP 4096
#define DC     4096
#define NB     4
#define DB     2048
#define TBKT   5000

__device__ inline float block_reduce_sum(float v, float* sm) {
    #pragma unroll
    for (int off = 32; off > 0; off >>= 1) v += __shfl_down(v, off);
    int lane = threadIdx.x & 63;
    int wid  = threadIdx.x >> 6;
    if (lane == 0) sm[wid] = v;
    __syncthreads();
    float r = 0.f;
    if (wid == 0) {
        r = (lane < 4) ? sm[lane] : 0.f;
        r += __shfl_down(r, 2);
        r += __shfl_down(r, 1);
    }
    return r;  // valid on thread 0
}

// Weighted squared-error sums: region 0 = common (4096x4096),
// regions 1..4 = blocks (4096x2048 each). atomicAdd partial into ws[region].
__global__ __launch_bounds__(256) void wse_reduce_kernel(
    const float* __restrict__ ct, const float* __restrict__ cr,
    const float* __restrict__ bt, const float* __restrict__ br,
    const float* __restrict__ sw, float* __restrict__ ws)
{
    const int region = blockIdx.y;
    const float4* a;
    const float4* b;
    int nvec, rowShift;
    if (region == 0) {
        a = (const float4*)ct; b = (const float4*)cr;
        nvec = (N_SAMP * DC) / 4;      // 4,194,304 vec4
        rowShift = 10;                 // 1024 vec4 per row
    } else {
        long off = (long)(region - 1) * N_SAMP * DB;
        a = (const float4*)(bt + off); b = (const float4*)(br + off);
        nvec = (N_SAMP * DB) / 4;      // 2,097,152 vec4
        rowShift = 9;                  // 512 vec4 per row
    }
    float acc = 0.f;
    const int stride = gridDim.x * blockDim.x;
    for (int v = blockIdx.x * blockDim.x + threadIdx.x; v < nvec; v += stride) {
        float4 x = b[v];               // recon
        float4 y = a[v];               // target
        float w  = sw[v >> rowShift];
        float d0 = x.x - y.x, d1 = x.y - y.y, d2 = x.z - y.z, d3 = x.w - y.w;
        acc += w * (d0 * d0 + d1 * d1 + d2 * d2 + d3 * d3);
    }
    __shared__ float sm[4];
    float total = block_reduce_sum(acc, sm);
    if (threadIdx.x == 0) atomicAdd(&ws[region], total);
}

// One block per Cox loss: blockIdx.x==0 -> pred (out[0]),
// blockIdx.x==b+1 -> block_hazards[b] (out[6+b]).
// risk[i] = suffix_sum over time buckets of exp(pred[j]).
__global__ __launch_bounds__(256) void cox_kernel(
    const float* __restrict__ pred, const float* __restrict__ haz,
    const float* __restrict__ sw, const int* __restrict__ st,
    const int* __restrict__ se, float* __restrict__ out)
{
    const int CH = 20;                 // 256*20 = 5120 >= 5000 buckets
    __shared__ float hist[TBKT];
    __shared__ float scan[256];
    __shared__ float sm1[4], sm2[4];

    const int c   = blockIdx.x;
    const int tid = threadIdx.x;
    const float* p = (c == 0) ? pred : (haz + (long)(c - 1) * N_SAMP);

    for (int i = tid; i < TBKT; i += 256) hist[i] = 0.f;
    __syncthreads();

    for (int j = tid; j < N_SAMP; j += 256) {
        int t = st[j];
        t = (t < 0) ? 0 : ((t >= TBKT) ? TBKT - 1 : t);
        atomicAdd(&hist[t], expf(p[j]));
    }
    __syncthreads();

    // chunk sums
    const int base = tid * CH;
    float cs = 0.f;
    for (int i = base; i < base + CH && i < TBKT; ++i) cs += hist[i];
    scan[tid] = cs;
    __syncthreads();
    // Hillis-Steele suffix scan across 256 chunks
    for (int off = 1; off < 256; off <<= 1) {
        float v = (tid + off < 256) ? scan[tid + off] : 0.f;
        __syncthreads();
        scan[tid] += v;
        __syncthreads();
    }
    // within-chunk suffix; hist[t] becomes S[t] = sum_{u>=t} hist_orig[u]
    float run = (tid < 255) ? scan[tid + 1] : 0.f;
    int hi = base + CH; if (hi > TBKT) hi = TBKT;
    for (int i = hi - 1; i >= base; --i) { run += hist[i]; hist[i] = run; }
    __syncthreads();

    float s = 0.f, ne = 0.f;
    for (int j = tid; j < N_SAMP; j += 256) {
        float e = (float)se[j];
        int t = st[j];
        t = (t < 0) ? 0 : ((t >= TBKT) ? TBKT - 1 : t);
        s  += sw[j] * e * (p[j] - logf(hist[t]));
        ne += e;
    }
    float S  = block_reduce_sum(s, sm1);
    float NE = block_reduce_sum(ne, sm2);
    if (tid == 0) {
        float loss = (NE > 0.f) ? (-S / fmaxf(NE, 1.f)) : 0.f;
        out[(c == 0) ? 0 : (5 + c)] = loss;
    }
}

__global__ void finalize_kernel(const float* __restrict__ ws,
                                float* __restrict__ out)
{
    int i = threadIdx.x;
    if (i == 0)      out[1]     = ws[0] * (1.f / (float)DC);
    else if (i < 5)  out[1 + i] = ws[i] * (1.f / (float)DB);
}

extern "C" void kernel_launch(void* const* d_in, const int* in_sizes, int n_in,
                              void* d_out, int out_size, void* d_ws, size_t ws_size,
                              hipStream_t stream) {
    const float* pred = (const float*)d_in[0];
    const float* ct   = (const float*)d_in[1];
    const float* cr   = (const float*)d_in[2];
    const float* bt   = (const float*)d_in[3];
    const float* br   = (const float*)d_in[4];
    const float* bh   = (const float*)d_in[5];
    const float* sw   = (const float*)d_in[6];
    const int*   st   = (const int*)d_in[7];
    const int*   se   = (const int*)d_in[8];
    float* out = (float*)d_out;
    float* ws  = (float*)d_ws;

    hipMemsetAsync(ws, 0, 5 * sizeof(float), stream);

    dim3 grid(1024, 5);
    wse_reduce_kernel<<<grid, 256, 0, stream>>>(ct, cr, bt, br, sw, ws);
    cox_kernel<<<5, 256, 0, stream>>>(pred, bh, sw, st, se, out);
    finalize_kernel<<<1, 64, 0, stream>>>(ws, out);
}

// Round 2
// 103.370 us; speedup vs baseline: 1.2206x; 1.2206x over previous
//
#include <hip/hip_runtime.h>
#include <hip/hip_bf16.h>

// Problem constants (fixed by setup_inputs):
//   n = 4096, dc = 4096, nb = 4, db = 2048, T buckets = 5000
#define N_SAMP 4096
#define DC     4096
#define NB     4
#define DB     2048
#define TBKT   5000

#define CVEC (N_SAMP * DC / 4)   // 4,194,304 vec4 in common region
#define BVEC (N_SAMP * DB / 4)   // 2,097,152 vec4 per block region
#define TILE 4096                // vec4 per workgroup (divides BVEC and CVEC)
#define NTILES ((CVEC + NB * BVEC) / TILE)  // 3072

__device__ inline float block_reduce_sum(float v, float* sm) {
    #pragma unroll
    for (int off = 32; off > 0; off >>= 1) v += __shfl_down(v, off);
    int lane = threadIdx.x & 63;
    int wid  = threadIdx.x >> 6;
    if (lane == 0) sm[wid] = v;
    __syncthreads();
    float r = 0.f;
    if (wid == 0) {
        r = (lane < 4) ? sm[lane] : 0.f;
        r += __shfl_down(r, 2);
        r += __shfl_down(r, 1);
    }
    return r;  // valid on thread 0
}

// Weighted squared-error sums. Each block owns one contiguous TILE of vec4s
// lying entirely inside one region. 16 vec4/thread, unrolled 8-deep so ~17
// loads are in flight per wave before the first consume (MLP fix for R0's
// 1.5 TB/s latency-bound result).
__global__ __launch_bounds__(256) void wse_reduce_kernel(
    const float* __restrict__ ct, const float* __restrict__ cr,
    const float* __restrict__ bt, const float* __restrict__ br,
    const float* __restrict__ sw, float* __restrict__ ws)
{
    const int tile = blockIdx.x;
    const int vstart = tile * TILE;          // < 12.6M, fits int
    const float4* a;
    const float4* b;
    int region, rowShift, vloc;
    if (vstart < CVEC) {
        region = 0; rowShift = 10;           // 1024 vec4 per row
        a = (const float4*)ct; b = (const float4*)cr;
        vloc = vstart;
    } else {
        const int q   = vstart - CVEC;
        const int blk = q / BVEC;
        region = 1 + blk; rowShift = 9;      // 512 vec4 per row
        a = (const float4*)bt + (long)blk * BVEC;
        b = (const float4*)br + (long)blk * BVEC;
        vloc = q - blk * BVEC;
    }
    const int v0 = vloc + threadIdx.x;

    float acc = 0.f;
    #pragma unroll
    for (int outer = 0; outer < 2; ++outer) {
        float4 xa[8], ya[8];
        float  wv[8];
        const int base = v0 + outer * 2048;
        #pragma unroll
        for (int i = 0; i < 8; ++i) {
            xa[i] = b[base + i * 256];
            ya[i] = a[base + i * 256];
            wv[i] = sw[(base + i * 256) >> rowShift];
        }
        #pragma unroll
        for (int i = 0; i < 8; ++i) {
            float d0 = xa[i].x - ya[i].x, d1 = xa[i].y - ya[i].y;
            float d2 = xa[i].z - ya[i].z, d3 = xa[i].w - ya[i].w;
            acc += wv[i] * (d0 * d0 + d1 * d1 + d2 * d2 + d3 * d3);
        }
    }

    __shared__ float sm[4];
    float total = block_reduce_sum(acc, sm);
    if (threadIdx.x == 0) atomicAdd(&ws[region], total);
}

// One block per Cox loss: blockIdx.x==0 -> pred (out[0]),
// blockIdx.x==b+1 -> block_hazards[b] (out[6+b]).
// risk[i] = suffix_sum over time buckets of exp(pred[j]).
__global__ __launch_bounds__(256) void cox_kernel(
    const float* __restrict__ pred, const float* __restrict__ haz,
    const float* __restrict__ sw, const int* __restrict__ st,
    const int* __restrict__ se, float* __restrict__ out)
{
    const int CH = 20;                 // 256*20 = 5120 >= 5000 buckets
    __shared__ float hist[TBKT];
    __shared__ float scan[256];
    __shared__ float sm1[4], sm2[4];

    const int c   = blockIdx.x;
    const int tid = threadIdx.x;
    const float* p = (c == 0) ? pred : (haz + (long)(c - 1) * N_SAMP);

    for (int i = tid; i < TBKT; i += 256) hist[i] = 0.f;
    __syncthreads();

    for (int j = tid; j < N_SAMP; j += 256) {
        int t = st[j];
        t = (t < 0) ? 0 : ((t >= TBKT) ? TBKT - 1 : t);
        atomicAdd(&hist[t], expf(p[j]));
    }
    __syncthreads();

    // chunk sums
    const int base = tid * CH;
    float cs = 0.f;
    for (int i = base; i < base + CH && i < TBKT; ++i) cs += hist[i];
    scan[tid] = cs;
    __syncthreads();
    // Hillis-Steele suffix scan across 256 chunks
    for (int off = 1; off < 256; off <<= 1) {
        float v = (tid + off < 256) ? scan[tid + off] : 0.f;
        __syncthreads();
        scan[tid] += v;
        __syncthreads();
    }
    // within-chunk suffix; hist[t] becomes S[t] = sum_{u>=t} hist_orig[u]
    float run = (tid < 255) ? scan[tid + 1] : 0.f;
    int hi = base + CH; if (hi > TBKT) hi = TBKT;
    for (int i = hi - 1; i >= base; --i) { run += hist[i]; hist[i] = run; }
    __syncthreads();

    float s = 0.f, ne = 0.f;
    for (int j = tid; j < N_SAMP; j += 256) {
        float e = (float)se[j];
        int t = st[j];
        t = (t < 0) ? 0 : ((t >= TBKT) ? TBKT - 1 : t);
        s  += sw[j] * e * (p[j] - logf(hist[t]));
        ne += e;
    }
    float S  = block_reduce_sum(s, sm1);
    float NE = block_reduce_sum(ne, sm2);
    if (tid == 0) {
        float loss = (NE > 0.f) ? (-S / fmaxf(NE, 1.f)) : 0.f;
        out[(c == 0) ? 0 : (5 + c)] = loss;
    }
}

__global__ void finalize_kernel(const float* __restrict__ ws,
                                float* __restrict__ out)
{
    int i = threadIdx.x;
    if (i == 0)      out[1]     = ws[0] * (1.f / (float)DC);
    else if (i < 5)  out[1 + i] = ws[i] * (1.f / (float)DB);
}

extern "C" void kernel_launch(void* const* d_in, const int* in_sizes, int n_in,
                              void* d_out, int out_size, void* d_ws, size_t ws_size,
                              hipStream_t stream) {
    const float* pred = (const float*)d_in[0];
    const float* ct   = (const float*)d_in[1];
    const float* cr   = (const float*)d_in[2];
    const float* bt   = (const float*)d_in[3];
    const float* br   = (const float*)d_in[4];
    const float* bh   = (const float*)d_in[5];
    const float* sw   = (const float*)d_in[6];
    const int*   st   = (const int*)d_in[7];
    const int*   se   = (const int*)d_in[8];
    float* out = (float*)d_out;
    float* ws  = (float*)d_ws;

    hipMemsetAsync(ws, 0, 5 * sizeof(float), stream);

    wse_reduce_kernel<<<NTILES, 256, 0, stream>>>(ct, cr, bt, br, sw, ws);
    cox_kernel<<<5, 256, 0, stream>>>(pred, bh, sw, st, se, out);
    finalize_kernel<<<1, 64, 0, stream>>>(ws, out);
}